// Round 2
// baseline (210.546 us; speedup 1.0000x reference)
//
#include <hip/hip_runtime.h>
#include <math.h>

#define S_LEN   4032
#define HOURS   24
#define DAYS    168
#define WPS     3            // waves per sample (3*64 = 192 >= 168 days)

// ---------------- kernel A: one wave per 64 days, no LDS, no syncs ----------------
// wave w: sample b = w/3, days [64*(w%3), +64). Per-wave partial outputs:
// Apart[w]=sum true_peak, Ppart[w]=sum (dpeak)^2, SEpart, SWpart, Tpart.

__global__ __launch_bounds__(256) void day_kernel(
    const float* __restrict__ y_pred, const float* __restrict__ y_true,
    float* __restrict__ Apart, float* __restrict__ Ppart,
    float* __restrict__ SEpart, float* __restrict__ SWpart, float* __restrict__ Tpart,
    int nW)
{
    const int lane = threadIdx.x & 63;
    const int w = blockIdx.x * 4 + (threadIdx.x >> 6);
    if (w >= nW) return;
    const int b = w / WPS;
    const int part = w - b * WPS;
    const int day = part * 64 + lane;
    const bool active = day < DAYS;
    const int dc = active ? day : (DAYS - 1);

    const float4* gt = (const float4*)(y_true + (size_t)b * S_LEN + (size_t)dc * HOURS);
    const float4* gp = (const float4*)(y_pred + (size_t)b * S_LEN + (size_t)dc * HOURS);

    // issue all 12 loads up front for MLP
    float yt[24], yp[24];
    {
        float4 t0 = gt[0], t1 = gt[1], t2 = gt[2], t3 = gt[3], t4 = gt[4], t5 = gt[5];
        float4 p0 = gp[0], p1 = gp[1], p2 = gp[2], p3 = gp[3], p4 = gp[4], p5 = gp[5];
        yt[0]=t0.x; yt[1]=t0.y; yt[2]=t0.z; yt[3]=t0.w;
        yt[4]=t1.x; yt[5]=t1.y; yt[6]=t1.z; yt[7]=t1.w;
        yt[8]=t2.x; yt[9]=t2.y; yt[10]=t2.z; yt[11]=t2.w;
        yt[12]=t3.x; yt[13]=t3.y; yt[14]=t3.z; yt[15]=t3.w;
        yt[16]=t4.x; yt[17]=t4.y; yt[18]=t4.z; yt[19]=t4.w;
        yt[20]=t5.x; yt[21]=t5.y; yt[22]=t5.z; yt[23]=t5.w;
        yp[0]=p0.x; yp[1]=p0.y; yp[2]=p0.z; yp[3]=p0.w;
        yp[4]=p1.x; yp[5]=p1.y; yp[6]=p1.z; yp[7]=p1.w;
        yp[8]=p2.x; yp[9]=p2.y; yp[10]=p2.z; yp[11]=p2.w;
        yp[12]=p3.x; yp[13]=p3.y; yp[14]=p3.z; yp[15]=p3.w;
        yp[16]=p4.x; yp[17]=p4.y; yp[18]=p4.z; yp[19]=p4.w;
        yp[20]=p5.x; yp[21]=p5.y; yp[22]=p5.z; yp[23]=p5.w;
    }

    // daytime argmax, strict > in ascending h == first-max (jnp.argmax)
    float tbest = yt[6]; int tt = 6;
#pragma unroll
    for (int h = 7; h <= 20; ++h) if (yt[h] > tbest) { tbest = yt[h]; tt = h; }
    float pbest = yp[6]; int pt = 6;
#pragma unroll
    for (int h = 7; h <= 20; ++h) if (yp[h] > pbest) { pbest = yp[h]; pt = h; }

    float se = 0.f, sw = 0.f;
#pragma unroll
    for (int h = 0; h < 24; ++h) {
        const bool dayh = (h >= 6) && (h <= 20);
        const float bw = dayh ? 2.0f : 0.5f;
        float wg = bw * (((h >= tt - 2) && (h <= tt + 2)) ? 3.0f : 1.0f);
        float d = yp[h] - yt[h];
        se = fmaf(d * d, wg, se);
        sw += wg;
    }

    float tpeak = tbest;
    float dp = pbest - tbest;
    float psq = dp * dp;
    float terr = fabsf((float)(pt - tt));
    if (!active) { tpeak = 0.f; psq = 0.f; se = 0.f; sw = 0.f; terr = 0.f; }

#pragma unroll
    for (int o = 32; o > 0; o >>= 1) {
        tpeak += __shfl_down(tpeak, o, 64);
        psq   += __shfl_down(psq,   o, 64);
        se    += __shfl_down(se,    o, 64);
        sw    += __shfl_down(sw,    o, 64);
        terr  += __shfl_down(terr,  o, 64);
    }
    if (lane == 0) {
        Apart[w] = tpeak; Ppart[w] = psq; SEpart[w] = se; SWpart[w] = sw; Tpart[w] = terr;
    }
}

// ---------------- kernel B: quantile (radix select, wave-aggregated) + final scalar ----------------

__device__ inline double block_reduce_d(double v, double* scratch, int tid) {
#pragma unroll
    for (int o = 32; o > 0; o >>= 1) v += __shfl_down(v, o, 64);
    if ((tid & 63) == 0) scratch[tid >> 6] = v;
    __syncthreads();
    double r = 0.0;
    if (tid == 0) r = scratch[0] + scratch[1] + scratch[2] + scratch[3];
    __syncthreads();
    return r;
}

#define NB_MAX 4096

__global__ __launch_bounds__(256) void finalize_kernel(
    const float* __restrict__ Apart, const float* __restrict__ Ppart,
    const float* __restrict__ SEpart, const float* __restrict__ SWpart,
    const float* __restrict__ Tpart, float* __restrict__ out, int nB, int nW)
{
    __shared__ unsigned s_keys[NB_MAX];
    __shared__ unsigned s_hist[256];
    __shared__ unsigned s_wtot[4];
    __shared__ unsigned s_sel, s_srem;
    __shared__ double s_dred[4];

    const int tid = threadIdx.x;
    const int lane = tid & 63;

    // A[b] = (sum of 3 wave partials)/168; store as sortable uint key
    for (int i = tid; i < nB; i += 256) {
        float a = (Apart[3 * i] + Apart[3 * i + 1] + Apart[3 * i + 2]) * (1.0f / (float)DAYS);
        unsigned u = __float_as_uint(a);
        s_keys[i] = (u & 0x80000000u) ? ~u : (u | 0x80000000u);
    }
    __syncthreads();

    double pos = 0.75 * (double)(nB - 1);
    int lo = (int)pos;
    double frac = pos - (double)lo;
    int ranks[2] = {lo, (lo + 1 < nB) ? lo + 1 : lo};
    float qv[2];

    for (int sidx = 0; sidx < 2; ++sidx) {
        int rem = ranks[sidx];
        unsigned prefix = 0;
        for (int shift = 24; shift >= 0; shift -= 8) {
            s_hist[tid] = 0;
            __syncthreads();
            unsigned maskAbove = (shift == 24) ? 0u : (0xFFFFFFFFu << (shift + 8));
            for (int i = tid; i < nB; i += 256) {   // nB % 256 == 0: wave-uniform loop
                unsigned k = s_keys[i];
                bool act = ((k & maskAbove) == prefix);
                unsigned digit = (k >> shift) & 0xFFu;
                // wave-aggregated increment: one atomic per distinct digit per wave
                unsigned long long peers = __ballot(act);
#pragma unroll
                for (int bit = 0; bit < 8; ++bit) {
                    bool mine = (digit >> bit) & 1u;
                    unsigned long long vote = __ballot(act && mine);
                    peers &= mine ? vote : ~vote;
                }
                if (act) {
                    int leader = __ffsll((unsigned long long)peers) - 1;
                    if (lane == leader)
                        atomicAdd(&s_hist[digit], (unsigned)__popcll(peers));
                }
            }
            __syncthreads();
            unsigned c = s_hist[tid];
            unsigned x = c;
#pragma unroll
            for (int o = 1; o < 64; o <<= 1) {
                unsigned y = __shfl_up(x, o, 64);
                if ((tid & 63) >= o) x += y;
            }
            if ((tid & 63) == 63) s_wtot[tid >> 6] = x;
            __syncthreads();
            unsigned woff = 0;
            for (int w2 = 0; w2 < (tid >> 6); ++w2) woff += s_wtot[w2];
            unsigned incl = woff + x;
            unsigned excl = incl - c;
            if ((unsigned)rem >= excl && (unsigned)rem < incl) {
                s_sel = (unsigned)tid;
                s_srem = (unsigned)rem - excl;
            }
            __syncthreads();
            prefix |= (s_sel << shift);
            rem = (int)s_srem;
            __syncthreads();
        }
        unsigned bits = (prefix & 0x80000000u) ? (prefix & 0x7FFFFFFFu) : ~prefix;
        qv[sidx] = __uint_as_float(bits);
    }

    float thr = (float)((double)qv[0] + frac * ((double)qv[1] - (double)qv[0]));
    unsigned tu = __float_as_uint(thr);
    unsigned thrKey = (tu & 0x80000000u) ? ~tu : (tu | 0x80000000u);

    double wp = 0.0, wsum = 0.0, se = 0.0, swt = 0.0, te = 0.0;
    for (int i = tid; i < nB; i += 256) {
        float w = (s_keys[i] > thrKey) ? 1.5f : 1.0f;   // monotone key transform
        float Pb = Ppart[3 * i] + Ppart[3 * i + 1] + Ppart[3 * i + 2];
        wp   += (double)w * (double)Pb;
        wsum += (double)w;
    }
    for (int i = tid; i < nW; i += 256) {
        se  += (double)SEpart[i];
        swt += (double)SWpart[i];
        te  += (double)Tpart[i];
    }
    wp   = block_reduce_d(wp,   s_dred, tid);
    wsum = block_reduce_d(wsum, s_dred, tid);
    se   = block_reduce_d(se,   s_dred, tid);
    swt  = block_reduce_d(swt,  s_dred, tid);
    te   = block_reduce_d(te,   s_dred, tid);

    if (tid == 0) {
        double L_overall = se / swt;
        double L_peak    = wp / ((double)DAYS * wsum);
        double L_timing  = 10.0 * te / ((double)nB * (double)DAYS);
        out[0] = (float)(L_overall + 2.0 * L_peak + L_timing);
    }
}

// ---------------- launcher ----------------

extern "C" void kernel_launch(void* const* d_in, const int* in_sizes, int n_in,
                              void* d_out, int out_size, void* d_ws, size_t ws_size,
                              hipStream_t stream) {
    const float* y_pred = (const float*)d_in[0];
    const float* y_true = (const float*)d_in[1];
    int total = in_sizes[0];
    int nB = total / S_LEN;          // 4096 for reference shapes
    int nW = nB * WPS;               // 12288 waves

    float* ws    = (float*)d_ws;
    float* Apart = ws;
    float* Ppart = ws + 1 * (size_t)nW;
    float* SEp   = ws + 2 * (size_t)nW;
    float* SWp   = ws + 3 * (size_t)nW;
    float* Tp    = ws + 4 * (size_t)nW;

    int nBlocks = (nW + 3) / 4;      // 4 waves per 256-thread block
    day_kernel<<<nBlocks, 256, 0, stream>>>(y_pred, y_true, Apart, Ppart, SEp, SWp, Tp, nW);
    finalize_kernel<<<1, 256, 0, stream>>>(Apart, Ppart, SEp, SWp, Tp, (float*)d_out, nB, nW);
}

// Round 3
// 188.156 us; speedup vs baseline: 1.1190x; 1.1190x over previous
//
#include <hip/hip_runtime.h>
#include <math.h>

#define S_LEN   4032
#define HOURS   24
#define DAYS    168
#define DPB     42           // days per block (42*24 = 1008 floats = 252 float4)
#define ACT     252          // active threads per 256-block
#define QPB     4            // blocks per sample (168/42)
#define NB_MAX  4096

// ================= kernel A: hour-major coalesced, one block = 42 days =================
// block id = b*4 + q. Outputs per block: SEp, SWp, Tp (day-sums), Pp (sum dpeak^2),
// Ap (sum true peaks).

__global__ __launch_bounds__(256, 8) void day_kernel(
    const float* __restrict__ y_pred, const float* __restrict__ y_true,
    float* __restrict__ SEp, float* __restrict__ SWp, float* __restrict__ Tp,
    float* __restrict__ Pp, float* __restrict__ Ap)
{
    __shared__ float s_tv[ACT], s_pv[ACT];
    __shared__ int   s_th[ACT], s_ph[ACT];
    __shared__ int   s_tt[DPB];
    __shared__ float s_red[5][4];

    const int tid = threadIdx.x;
    const int lane = tid & 63;
    const int wv = tid >> 6;

    float se = 0.f, sw = 0.f, ap = 0.f, pp = 0.f, tp = 0.f;

    float yp[4], yt[4];
    int j = tid % 6;                       // float4 index within the day
    int dl = tid / 6;                      // local day [0,42)

    if (tid < ACT) {
        const size_t base = (size_t)blockIdx.x * (DPB * HOURS) + (size_t)tid * 4;
        float4 p4 = *(const float4*)(y_pred + base);
        float4 t4 = *(const float4*)(y_true + base);
        yp[0] = p4.x; yp[1] = p4.y; yp[2] = p4.z; yp[3] = p4.w;
        yt[0] = t4.x; yt[1] = t4.y; yt[2] = t4.z; yt[3] = t4.w;

        // per-thread daytime max/argmax candidates (ascending h, strict > = first-max)
        float tv = -1e30f, pv = -1e30f; int th = 0, ph = 0;
#pragma unroll
        for (int k = 0; k < 4; ++k) {
            int h = 4 * j + k;
            bool day = (h >= 6) && (h <= 20);
            if (day && yt[k] > tv) { tv = yt[k]; th = h; }
            if (day && yp[k] > pv) { pv = yp[k]; ph = h; }
        }
        s_tv[tid] = tv; s_th[tid] = th;
        s_pv[tid] = pv; s_ph[tid] = ph;
    }
    __syncthreads();

    if (tid < DPB) {
        int o = tid * 6;
        float tb = s_tv[o]; int tt = s_th[o];
        float pb = s_pv[o]; int pt = s_ph[o];
#pragma unroll
        for (int jj = 1; jj < 6; ++jj) {
            float v = s_tv[o + jj];
            if (v > tb) { tb = v; tt = s_th[o + jj]; }
            float w = s_pv[o + jj];
            if (w > pb) { pb = w; pt = s_ph[o + jj]; }
        }
        s_tt[tid] = tt;
        ap = tb;
        float dp = pb - tb;
        pp = dp * dp;
        tp = fabsf((float)(pt - tt));
    }
    __syncthreads();

    if (tid < ACT) {
        int tt = s_tt[dl];
#pragma unroll
        for (int k = 0; k < 4; ++k) {
            int h = 4 * j + k;
            bool day = (h >= 6) && (h <= 20);
            float bw = day ? 2.0f : 0.5f;
            float w = bw * (((h >= tt - 2) && (h <= tt + 2)) ? 3.0f : 1.0f);
            float d = yp[k] - yt[k];
            se = fmaf(d * d, w, se);
            sw += w;
        }
    }

    // block reduce 5 quantities, single barrier
    float vals[5] = {se, sw, ap, pp, tp};
#pragma unroll
    for (int q = 0; q < 5; ++q) {
        float v = vals[q];
#pragma unroll
        for (int o = 32; o > 0; o >>= 1) v += __shfl_down(v, o, 64);
        if (lane == 0) s_red[q][wv] = v;
    }
    __syncthreads();
    if (tid == 0) {
        SEp[blockIdx.x] = s_red[0][0] + s_red[0][1] + s_red[0][2] + s_red[0][3];
        SWp[blockIdx.x] = s_red[1][0] + s_red[1][1] + s_red[1][2] + s_red[1][3];
        Ap[blockIdx.x]  = s_red[2][0] + s_red[2][1] + s_red[2][2] + s_red[2][3];
        Pp[blockIdx.x]  = s_red[3][0] + s_red[3][1] + s_red[3][2] + s_red[3][3];
        Tp[blockIdx.x]  = s_red[4][0] + s_red[4][1] + s_red[4][2] + s_red[4][3];
    }
}

// ================= kernel B: parallel rank-by-counting quantile =================
// 2 threads per sample; each block rebuilds A[] (all nB) in LDS from Ap parts.
// Threads whose value covers rank lo/hi write qout[0]/qout[1].

__global__ __launch_bounds__(256) void rank_kernel(
    const float* __restrict__ Ap, float* __restrict__ A_out,
    float* __restrict__ qout, int nB)
{
    __shared__ float sA[NB_MAX];
    const int tid = threadIdx.x;

    for (int i = tid; i < nB; i += 256) {
        float4 p = *(const float4*)(Ap + 4 * i);
        float a = (p.x + p.y + p.z + p.w) * (1.0f / (float)DAYS);
        sA[i] = a;
        if (blockIdx.x == 0) A_out[i] = a;
    }
    __syncthreads();

    const int b = blockIdx.x * 128 + (tid >> 1);
    const int half = tid & 1;
    if (b >= nB) return;
    const float v = sA[b];
    const int span = nB / 2;
    const float4* s4 = (const float4*)(sA + half * span);

    int cl = 0, ce = 0;
    for (int i = 0; i < span / 4; ++i) {
        float4 x = s4[i];
        cl += (x.x < v) + (x.y < v) + (x.z < v) + (x.w < v);
        ce += (x.x == v) + (x.y == v) + (x.z == v) + (x.w == v);
    }
    cl += __shfl_xor(cl, 1, 64);
    ce += __shfl_xor(ce, 1, 64);

    if (half == 0) {
        double pos = 0.75 * (double)(nB - 1);
        int lo = (int)pos;
        int hi = (lo + 1 < nB) ? lo + 1 : lo;
        if (lo >= cl && lo < cl + ce) qout[0] = v;
        if (hi >= cl && hi < cl + ce) qout[1] = v;
    }
}

// ================= kernel C: final scalar =================

__device__ inline double block_reduce_d(double v, double* scratch, int tid) {
#pragma unroll
    for (int o = 32; o > 0; o >>= 1) v += __shfl_down(v, o, 64);
    if ((tid & 63) == 0) scratch[tid >> 6] = v;
    __syncthreads();
    double r = 0.0;
    if (tid == 0) r = scratch[0] + scratch[1] + scratch[2] + scratch[3];
    __syncthreads();
    return r;
}

__global__ __launch_bounds__(256) void final_kernel(
    const float* __restrict__ SEp, const float* __restrict__ SWp,
    const float* __restrict__ Tp, const float* __restrict__ Pp,
    const float* __restrict__ A, const float* __restrict__ qout,
    float* __restrict__ out, int nB)
{
    __shared__ double s_dred[4];
    const int tid = threadIdx.x;
    const int nBlk = nB * QPB;

    double pos = 0.75 * (double)(nB - 1);
    double frac = pos - (double)((int)pos);
    float thr = (float)((double)qout[0] + frac * ((double)qout[1] - (double)qout[0]));

    double se = 0.0, sw = 0.0, te = 0.0, wp = 0.0, wsum = 0.0;
    for (int i = tid; i < nBlk; i += 256) {
        se += (double)SEp[i];
        sw += (double)SWp[i];
        te += (double)Tp[i];
    }
    for (int b = tid; b < nB; b += 256) {
        float4 p = *(const float4*)(Pp + 4 * b);
        float Pb = p.x + p.y + p.z + p.w;
        float w = (A[b] > thr) ? 1.5f : 1.0f;
        wp   += (double)w * (double)Pb;
        wsum += (double)w;
    }
    se   = block_reduce_d(se,   s_dred, tid);
    sw   = block_reduce_d(sw,   s_dred, tid);
    te   = block_reduce_d(te,   s_dred, tid);
    wp   = block_reduce_d(wp,   s_dred, tid);
    wsum = block_reduce_d(wsum, s_dred, tid);

    if (tid == 0) {
        double L_overall = se / sw;
        double L_peak    = wp / ((double)DAYS * wsum);
        double L_timing  = 10.0 * te / ((double)nB * (double)DAYS);
        out[0] = (float)(L_overall + 2.0 * L_peak + L_timing);
    }
}

// ================= launcher =================

extern "C" void kernel_launch(void* const* d_in, const int* in_sizes, int n_in,
                              void* d_out, int out_size, void* d_ws, size_t ws_size,
                              hipStream_t stream) {
    const float* y_pred = (const float*)d_in[0];
    const float* y_true = (const float*)d_in[1];
    int total = in_sizes[0];
    int nB = total / S_LEN;              // 4096
    int nBlk = nB * QPB;                 // 16384

    float* ws  = (float*)d_ws;
    float* SEp = ws;
    float* SWp = ws + 1 * (size_t)nBlk;
    float* Tp  = ws + 2 * (size_t)nBlk;
    float* Pp  = ws + 3 * (size_t)nBlk;
    float* Ap  = ws + 4 * (size_t)nBlk;
    float* A   = ws + 5 * (size_t)nBlk;
    float* q   = ws + 5 * (size_t)nBlk + (size_t)nB;

    day_kernel<<<nBlk, 256, 0, stream>>>(y_pred, y_true, SEp, SWp, Tp, Pp, Ap);
    rank_kernel<<<(nB + 127) / 128, 256, 0, stream>>>(Ap, A, q, nB);
    final_kernel<<<1, 256, 0, stream>>>(SEp, SWp, Tp, Pp, A, q, (float*)d_out, nB);
}

// Round 4
// 185.922 us; speedup vs baseline: 1.1324x; 1.0120x over previous
//
#include <hip/hip_runtime.h>
#include <math.h>

#define HOURS   24
#define DPS     168          // days per sample
#define S_LEN   4032
#define DPC     10           // days per chunk (one wave: 60 active lanes)
#define NBLK    2048
#define NWAVES  (NBLK * 4)
#define NB_MAX  4096

// ================= kernel A: barrier-free wave-per-10-days =================
// Per-day outputs Aday[d] (true peak), Pday[d] ((dpeak)^2); per-wave partials
// SEp/SWp/Tp. No LDS, no __syncthreads.

__global__ __launch_bounds__(256, 8) void day_kernel(
    const float* __restrict__ yTrue, const float* __restrict__ yPred,
    float* __restrict__ Aday, float* __restrict__ Pday,
    float* __restrict__ SEp, float* __restrict__ SWp, float* __restrict__ Tp,
    long long totalDays, int nChunks)
{
    const int lane = threadIdx.x & 63;
    const int wIdx = (blockIdx.x << 2) | (threadIdx.x >> 6);
    const int base = (lane / 6) * 6;        // group base lane (even)
    const int j    = lane - base;           // float4 slot in day, 0..5
    const bool laneActive = (lane < 60);

    float se = 0.f, sw = 0.f, te = 0.f;

    float4 nT = make_float4(0.f, 0.f, 0.f, 0.f);
    float4 nP = make_float4(0.f, 0.f, 0.f, 0.f);
    int c = wIdx;
    if (c < nChunks) {
        long long d = (long long)c * DPC + (base / 6);
        bool v = laneActive && (d < totalDays);
        size_t off = v ? ((size_t)d * HOURS + 4 * j) : 0;
        nT = *(const float4*)(yTrue + off);
        nP = *(const float4*)(yPred + off);
    }

    for (; c < nChunks; c += NWAVES) {
        float4 cT = nT, cP = nP;
        int cn = c + NWAVES;
        if (cn < nChunks) {
            long long d2 = (long long)cn * DPC + (base / 6);
            bool v2 = laneActive && (d2 < totalDays);
            size_t off2 = v2 ? ((size_t)d2 * HOURS + 4 * j) : 0;
            nT = *(const float4*)(yTrue + off2);
            nP = *(const float4*)(yPred + off2);
        }

        const long long d = (long long)c * DPC + (base / 6);
        const bool valid = laneActive && (d < totalDays);

        float yt[4] = {cT.x, cT.y, cT.z, cT.w};
        float yp[4] = {cP.x, cP.y, cP.z, cP.w};

        // per-lane daytime argmax candidates (ascending h, strict > = first-max)
        float tv = -1e30f, pv = -1e30f; int th = 0, ph = 0;
#pragma unroll
        for (int k = 0; k < 4; ++k) {
            int h = 4 * j + k;
            bool dayh = (h >= 6) && (h <= 20);
            if (dayh && yt[k] > tv) { tv = yt[k]; th = h; }
            if (dayh && yp[k] > pv) { pv = yp[k]; ph = h; }
        }
        if (!valid) { tv = -1e30f; pv = -1e30f; }

        // 6-lane group max: xor-pair then 3 bpermute gathers
        float m1t = fmaxf(tv, __shfl_xor(tv, 1, 64));
        float m1p = fmaxf(pv, __shfl_xor(pv, 1, 64));
        float gmt = fmaxf(fmaxf(__shfl(m1t, base, 64), __shfl(m1t, base + 2, 64)),
                          __shfl(m1t, base + 4, 64));
        float gmp = fmaxf(fmaxf(__shfl(m1p, base, 64), __shfl(m1p, base + 2, 64)),
                          __shfl(m1p, base + 4, 64));

        // argmax lane via ballot; first set bit in group = first max
        unsigned long long blt = __ballot(valid && (tv == gmt));
        unsigned long long blp = __ballot(valid && (pv == gmp));
        int ft = __ffsll(blt >> base) - 1;      // within-group lane of true peak
        int fp = __ffsll(blp >> base) - 1;
        int tt = __shfl(th, base + ft, 64);     // true peak hour (all lanes of group)
        int pt = __shfl(ph, base + fp, 64);

        if (valid) {
#pragma unroll
            for (int k = 0; k < 4; ++k) {
                int h = 4 * j + k;
                float bw = ((h >= 6) && (h <= 20)) ? 2.0f : 0.5f;
                float wgt = bw * (((h >= tt - 2) && (h <= tt + 2)) ? 3.0f : 1.0f);
                float dd = yp[k] - yt[k];
                se = fmaf(wgt * dd, dd, se);
                sw += wgt;
            }
            if (j == 0) {
                te += fabsf((float)(pt - tt));
                Aday[d] = gmt;
                float dpk = gmp - gmt;
                Pday[d] = dpk * dpk;
            }
        }
    }

    // one wave reduction at the end
#pragma unroll
    for (int o = 32; o > 0; o >>= 1) {
        se += __shfl_down(se, o, 64);
        sw += __shfl_down(sw, o, 64);
        te += __shfl_down(te, o, 64);
    }
    if (lane == 0) { SEp[wIdx] = se; SWp[wIdx] = sw; Tp[wIdx] = te; }
}

// ================= kernel B: per-sample reduce (168 days -> A[b], P[b]) =================

__global__ __launch_bounds__(64) void sample_kernel(
    const float* __restrict__ Aday, const float* __restrict__ Pday,
    float* __restrict__ A, float* __restrict__ P)
{
    const int b = blockIdx.x;
    const int lane = threadIdx.x;
    const float* ad = Aday + (size_t)b * DPS;
    const float* pd = Pday + (size_t)b * DPS;
    float sa = 0.f, sp = 0.f;
    for (int i = lane; i < DPS; i += 64) { sa += ad[i]; sp += pd[i]; }
#pragma unroll
    for (int o = 32; o > 0; o >>= 1) {
        sa += __shfl_down(sa, o, 64);
        sp += __shfl_down(sp, o, 64);
    }
    if (lane == 0) { A[b] = sa * (1.0f / (float)DPS); P[b] = sp; }
}

// ================= kernel C: parallel rank-by-counting quantile =================

__global__ __launch_bounds__(256) void rank_kernel(
    const float* __restrict__ A, float* __restrict__ qout, int nB)
{
    __shared__ float sA[NB_MAX];
    const int tid = threadIdx.x;

    for (int i = tid; i < nB; i += 256) sA[i] = A[i];
    __syncthreads();

    const int b = blockIdx.x * 128 + (tid >> 1);
    const int half = tid & 1;
    if (b >= nB) return;
    const float v = sA[b];
    const int span = nB / 2;
    const float4* s4 = (const float4*)(sA + half * span);

    int cl = 0, ce = 0;
    for (int i = 0; i < span / 4; ++i) {
        float4 x = s4[i];
        cl += (x.x < v) + (x.y < v) + (x.z < v) + (x.w < v);
        ce += (x.x == v) + (x.y == v) + (x.z == v) + (x.w == v);
    }
    cl += __shfl_xor(cl, 1, 64);
    ce += __shfl_xor(ce, 1, 64);

    if (half == 0) {
        double pos = 0.75 * (double)(nB - 1);
        int lo = (int)pos;
        int hi = (lo + 1 < nB) ? lo + 1 : lo;
        if (lo >= cl && lo < cl + ce) qout[0] = v;
        if (hi >= cl && hi < cl + ce) qout[1] = v;
    }
}

// ================= kernel D: final scalar =================

__device__ inline double block_reduce_d(double v, double* scratch, int tid) {
#pragma unroll
    for (int o = 32; o > 0; o >>= 1) v += __shfl_down(v, o, 64);
    if ((tid & 63) == 0) scratch[tid >> 6] = v;
    __syncthreads();
    double r = 0.0;
    if (tid == 0) r = scratch[0] + scratch[1] + scratch[2] + scratch[3];
    __syncthreads();
    return r;
}

__global__ __launch_bounds__(256) void final_kernel(
    const float* __restrict__ SEp, const float* __restrict__ SWp,
    const float* __restrict__ Tp, const float* __restrict__ P,
    const float* __restrict__ A, const float* __restrict__ qout,
    float* __restrict__ out, int nB, int nW)
{
    __shared__ double s_dred[4];
    const int tid = threadIdx.x;

    double pos = 0.75 * (double)(nB - 1);
    double frac = pos - (double)((int)pos);
    float thr = (float)((double)qout[0] + frac * ((double)qout[1] - (double)qout[0]));

    double se = 0.0, sw = 0.0, te = 0.0, wp = 0.0, wsum = 0.0;
    for (int i = tid; i < nW; i += 256) {
        se += (double)SEp[i];
        sw += (double)SWp[i];
        te += (double)Tp[i];
    }
    for (int b = tid; b < nB; b += 256) {
        float w = (A[b] > thr) ? 1.5f : 1.0f;
        wp   += (double)w * (double)P[b];
        wsum += (double)w;
    }
    se   = block_reduce_d(se,   s_dred, tid);
    sw   = block_reduce_d(sw,   s_dred, tid);
    te   = block_reduce_d(te,   s_dred, tid);
    wp   = block_reduce_d(wp,   s_dred, tid);
    wsum = block_reduce_d(wsum, s_dred, tid);

    if (tid == 0) {
        double L_overall = se / sw;
        double L_peak    = wp / ((double)DPS * wsum);
        double L_timing  = 10.0 * te / ((double)nB * (double)DPS);
        out[0] = (float)(L_overall + 2.0 * L_peak + L_timing);
    }
}

// ================= launcher =================

extern "C" void kernel_launch(void* const* d_in, const int* in_sizes, int n_in,
                              void* d_out, int out_size, void* d_ws, size_t ws_size,
                              hipStream_t stream) {
    const float* y_pred = (const float*)d_in[0];
    const float* y_true = (const float*)d_in[1];
    int total = in_sizes[0];
    int nB = total / S_LEN;                       // 4096
    long long totalDays = (long long)nB * DPS;    // 688128
    int nChunks = (int)((totalDays + DPC - 1) / DPC);

    float* ws   = (float*)d_ws;
    float* Aday = ws;
    float* Pday = Aday + (size_t)totalDays;
    float* SEp  = Pday + (size_t)totalDays;
    float* SWp  = SEp + NWAVES;
    float* Tp   = SWp + NWAVES;
    float* A    = Tp  + NWAVES;
    float* P    = A   + (size_t)nB;
    float* q    = P   + (size_t)nB;

    day_kernel<<<NBLK, 256, 0, stream>>>(y_true, y_pred, Aday, Pday, SEp, SWp, Tp,
                                         totalDays, nChunks);
    sample_kernel<<<nB, 64, 0, stream>>>(Aday, Pday, A, P);
    rank_kernel<<<(nB + 127) / 128, 256, 0, stream>>>(A, q, nB);
    final_kernel<<<1, 256, 0, stream>>>(SEp, SWp, Tp, P, A, q, (float*)d_out, nB, NWAVES);
}

// Round 5
// 169.729 us; speedup vs baseline: 1.2405x; 1.0954x over previous
//
#include <hip/hip_runtime.h>
#include <math.h>

#define HOURS   24
#define DPS     168          // days per sample
#define S_LEN   4032
#define NB_MAX  4096

// ================= kernel A: lane-per-day, register-only compute =================
// One day per lane. 2688 blocks x 256 threads for the reference shape.
// Outputs: Aday[d], Pday[d] (coalesced dword stores), per-block SEb/SWb/Tb.

__global__ __launch_bounds__(256) void day_kernel(
    const float* __restrict__ yTrue, const float* __restrict__ yPred,
    float* __restrict__ Aday, float* __restrict__ Pday,
    float* __restrict__ SEb, float* __restrict__ SWb, float* __restrict__ Tb,
    long long totalDays)
{
    __shared__ float s_red[3][4];
    const int tid = threadIdx.x;
    const int lane = tid & 63;
    const int wv = tid >> 6;

    const long long d = (long long)blockIdx.x * 256 + tid;
    const bool valid = d < totalDays;
    const long long dc = valid ? d : 0;

    const float4* gt = (const float4*)(yTrue + dc * HOURS);
    const float4* gp = (const float4*)(yPred + dc * HOURS);

    // issue all 12+12 loads up front (24 KB in flight per wave)
    float4 t0 = gt[0], t1 = gt[1], t2 = gt[2], t3 = gt[3], t4 = gt[4], t5 = gt[5];
    float4 p0 = gp[0], p1 = gp[1], p2 = gp[2], p3 = gp[3], p4 = gp[4], p5 = gp[5];

    float yt[24], yp[24];
    yt[0]=t0.x; yt[1]=t0.y; yt[2]=t0.z; yt[3]=t0.w;
    yt[4]=t1.x; yt[5]=t1.y; yt[6]=t1.z; yt[7]=t1.w;
    yt[8]=t2.x; yt[9]=t2.y; yt[10]=t2.z; yt[11]=t2.w;
    yt[12]=t3.x; yt[13]=t3.y; yt[14]=t3.z; yt[15]=t3.w;
    yt[16]=t4.x; yt[17]=t4.y; yt[18]=t4.z; yt[19]=t4.w;
    yt[20]=t5.x; yt[21]=t5.y; yt[22]=t5.z; yt[23]=t5.w;
    yp[0]=p0.x; yp[1]=p0.y; yp[2]=p0.z; yp[3]=p0.w;
    yp[4]=p1.x; yp[5]=p1.y; yp[6]=p1.z; yp[7]=p1.w;
    yp[8]=p2.x; yp[9]=p2.y; yp[10]=p2.z; yp[11]=p2.w;
    yp[12]=p3.x; yp[13]=p3.y; yp[14]=p3.z; yp[15]=p3.w;
    yp[16]=p4.x; yp[17]=p4.y; yp[18]=p4.z; yp[19]=p4.w;
    yp[20]=p5.x; yp[21]=p5.y; yp[22]=p5.z; yp[23]=p5.w;

    // daytime argmax, ascending h with strict > = first-max (jnp.argmax semantics)
    float tbest = yt[6]; int tt = 6;
#pragma unroll
    for (int h = 7; h <= 20; ++h) if (yt[h] > tbest) { tbest = yt[h]; tt = h; }
    float pbest = yp[6]; int pt = 6;
#pragma unroll
    for (int h = 7; h <= 20; ++h) if (yp[h] > pbest) { pbest = yp[h]; pt = h; }

    float se = 0.f, sw = 0.f;
#pragma unroll
    for (int h = 0; h < 24; ++h) {
        float bw = ((h >= 6) && (h <= 20)) ? 2.0f : 0.5f;
        float wgt = bw * (((h >= tt - 2) && (h <= tt + 2)) ? 3.0f : 1.0f);
        float dd = yp[h] - yt[h];
        se = fmaf(wgt * dd, dd, se);
        sw += wgt;
    }
    float te = fabsf((float)(pt - tt));
    if (!valid) { se = 0.f; sw = 0.f; te = 0.f; }

    if (valid) {
        Aday[d] = tbest;                 // coalesced dword stores
        float dpk = pbest - tbest;
        Pday[d] = dpk * dpk;
    }

    // wave reduce then block reduce the 3 scalars (one barrier, end of kernel)
#pragma unroll
    for (int o = 32; o > 0; o >>= 1) {
        se += __shfl_down(se, o, 64);
        sw += __shfl_down(sw, o, 64);
        te += __shfl_down(te, o, 64);
    }
    if (lane == 0) { s_red[0][wv] = se; s_red[1][wv] = sw; s_red[2][wv] = te; }
    __syncthreads();
    if (tid == 0) {
        SEb[blockIdx.x] = s_red[0][0] + s_red[0][1] + s_red[0][2] + s_red[0][3];
        SWb[blockIdx.x] = s_red[1][0] + s_red[1][1] + s_red[1][2] + s_red[1][3];
        Tb[blockIdx.x]  = s_red[2][0] + s_red[2][1] + s_red[2][2] + s_red[2][3];
    }
}

// ================= kernel B: per-sample reduce (168 days -> A[b], P[b]) =================

__global__ __launch_bounds__(64) void sample_kernel(
    const float* __restrict__ Aday, const float* __restrict__ Pday,
    float* __restrict__ A, float* __restrict__ P)
{
    const int b = blockIdx.x;
    const int lane = threadIdx.x;
    const float* ad = Aday + (size_t)b * DPS;
    const float* pd = Pday + (size_t)b * DPS;
    float sa = 0.f, sp = 0.f;
    for (int i = lane; i < DPS; i += 64) { sa += ad[i]; sp += pd[i]; }
#pragma unroll
    for (int o = 32; o > 0; o >>= 1) {
        sa += __shfl_down(sa, o, 64);
        sp += __shfl_down(sp, o, 64);
    }
    if (lane == 0) { A[b] = sa * (1.0f / (float)DPS); P[b] = sp; }
}

// ================= kernel C: parallel rank-by-counting quantile =================
// 4 threads per sample; 64 samples per block; each block holds all A in LDS.

__global__ __launch_bounds__(256) void rank_kernel(
    const float* __restrict__ A, float* __restrict__ qout, int nB)
{
    __shared__ float sA[NB_MAX];
    const int tid = threadIdx.x;

    for (int i = tid; i < nB; i += 256) sA[i] = A[i];
    __syncthreads();

    const int b = blockIdx.x * 64 + (tid >> 2);
    const int quar = tid & 3;
    if (b >= nB) return;
    const float v = sA[b];
    const int span = nB / 4;
    const float4* s4 = (const float4*)(sA + quar * span);

    int cl = 0, ce = 0;
    for (int i = 0; i < span / 4; ++i) {
        float4 x = s4[i];
        cl += (x.x < v) + (x.y < v) + (x.z < v) + (x.w < v);
        ce += (x.x == v) + (x.y == v) + (x.z == v) + (x.w == v);
    }
    cl += __shfl_xor(cl, 1, 64); ce += __shfl_xor(ce, 1, 64);
    cl += __shfl_xor(cl, 2, 64); ce += __shfl_xor(ce, 2, 64);

    if (quar == 0) {
        double pos = 0.75 * (double)(nB - 1);
        int lo = (int)pos;
        int hi = (lo + 1 < nB) ? lo + 1 : lo;
        if (lo >= cl && lo < cl + ce) qout[0] = v;
        if (hi >= cl && hi < cl + ce) qout[1] = v;
    }
}

// ================= kernel D: final scalar =================

__device__ inline double block_reduce_d(double v, double* scratch, int tid) {
#pragma unroll
    for (int o = 32; o > 0; o >>= 1) v += __shfl_down(v, o, 64);
    if ((tid & 63) == 0) scratch[tid >> 6] = v;
    __syncthreads();
    double r = 0.0;
    if (tid == 0) r = scratch[0] + scratch[1] + scratch[2] + scratch[3];
    __syncthreads();
    return r;
}

__global__ __launch_bounds__(256) void final_kernel(
    const float* __restrict__ SEb, const float* __restrict__ SWb,
    const float* __restrict__ Tb, const float* __restrict__ P,
    const float* __restrict__ A, const float* __restrict__ qout,
    float* __restrict__ out, int nB, int nBlk)
{
    __shared__ double s_dred[4];
    const int tid = threadIdx.x;

    double pos = 0.75 * (double)(nB - 1);
    double frac = pos - (double)((int)pos);
    float thr = (float)((double)qout[0] + frac * ((double)qout[1] - (double)qout[0]));

    double se = 0.0, sw = 0.0, te = 0.0, wp = 0.0, wsum = 0.0;
    for (int i = tid; i < nBlk; i += 256) {
        se += (double)SEb[i];
        sw += (double)SWb[i];
        te += (double)Tb[i];
    }
    for (int b = tid; b < nB; b += 256) {
        float w = (A[b] > thr) ? 1.5f : 1.0f;
        wp   += (double)w * (double)P[b];
        wsum += (double)w;
    }
    se   = block_reduce_d(se,   s_dred, tid);
    sw   = block_reduce_d(sw,   s_dred, tid);
    te   = block_reduce_d(te,   s_dred, tid);
    wp   = block_reduce_d(wp,   s_dred, tid);
    wsum = block_reduce_d(wsum, s_dred, tid);

    if (tid == 0) {
        double L_overall = se / sw;
        double L_peak    = wp / ((double)DPS * wsum);
        double L_timing  = 10.0 * te / ((double)nB * (double)DPS);
        out[0] = (float)(L_overall + 2.0 * L_peak + L_timing);
    }
}

// ================= launcher =================

extern "C" void kernel_launch(void* const* d_in, const int* in_sizes, int n_in,
                              void* d_out, int out_size, void* d_ws, size_t ws_size,
                              hipStream_t stream) {
    const float* y_pred = (const float*)d_in[0];
    const float* y_true = (const float*)d_in[1];
    int total = in_sizes[0];
    int nB = total / S_LEN;                       // 4096
    long long totalDays = (long long)nB * DPS;    // 688128
    int nBlk = (int)((totalDays + 255) / 256);    // 2688

    float* ws   = (float*)d_ws;
    float* Aday = ws;
    float* Pday = Aday + (size_t)totalDays;
    float* SEb  = Pday + (size_t)totalDays;
    float* SWb  = SEb + (size_t)nBlk;
    float* Tb   = SWb + (size_t)nBlk;
    float* A    = Tb  + (size_t)nBlk;
    float* P    = A   + (size_t)nB;
    float* q    = P   + (size_t)nB;

    day_kernel<<<nBlk, 256, 0, stream>>>(y_true, y_pred, Aday, Pday, SEb, SWb, Tb, totalDays);
    sample_kernel<<<nB, 64, 0, stream>>>(Aday, Pday, A, P);
    rank_kernel<<<(nB + 63) / 64, 256, 0, stream>>>(A, q, nB);
    final_kernel<<<1, 256, 0, stream>>>(SEb, SWb, Tb, P, A, q, (float*)d_out, nB, nBlk);
}

// Round 6
// 164.276 us; speedup vs baseline: 1.2817x; 1.0332x over previous
//
#include <hip/hip_runtime.h>
#include <math.h>

#define HOURS   24
#define DPS     168          // days per sample
#define S_LEN   4032
#define SPB     3            // samples per block (3*168 = 504 active of 512)
#define NB_MAX  4096

// ========== kernel A: fused day + per-sample reduce (512 thr = 3 samples) ==========
// Outputs: A[b] (mean true peak), P[b] (sum dpeak^2), per-block SEb/SWb/Tb.

__global__ __launch_bounds__(512) void day_kernel(
    const float* __restrict__ yTrue, const float* __restrict__ yPred,
    float* __restrict__ A, float* __restrict__ P,
    float* __restrict__ SEb, float* __restrict__ SWb, float* __restrict__ Tb,
    int nB)
{
    __shared__ float s_a[SPB * DPS + 8];   // true peak per local day
    __shared__ float s_p[SPB * DPS + 8];   // (dpeak)^2 per local day
    __shared__ float s_red[3][8];

    const int tid = threadIdx.x;
    const int lane = tid & 63;
    const int wv = tid >> 6;

    const int s  = tid / DPS;              // local sample slot 0..2 (3 for idle tail)
    const int ds = tid - s * DPS;          // day within sample
    const int b  = blockIdx.x * SPB + s;
    const bool valid = (tid < SPB * DPS) && (b < nB);

    const long long d = valid ? ((long long)b * DPS + ds) : 0;

    const float4* gt = (const float4*)(yTrue + d * HOURS);
    const float4* gp = (const float4*)(yPred + d * HOURS);

    float4 t0 = gt[0], t1 = gt[1], t2 = gt[2], t3 = gt[3], t4 = gt[4], t5 = gt[5];
    float4 p0 = gp[0], p1 = gp[1], p2 = gp[2], p3 = gp[3], p4 = gp[4], p5 = gp[5];

    float yt[24], yp[24];
    yt[0]=t0.x; yt[1]=t0.y; yt[2]=t0.z; yt[3]=t0.w;
    yt[4]=t1.x; yt[5]=t1.y; yt[6]=t1.z; yt[7]=t1.w;
    yt[8]=t2.x; yt[9]=t2.y; yt[10]=t2.z; yt[11]=t2.w;
    yt[12]=t3.x; yt[13]=t3.y; yt[14]=t3.z; yt[15]=t3.w;
    yt[16]=t4.x; yt[17]=t4.y; yt[18]=t4.z; yt[19]=t4.w;
    yt[20]=t5.x; yt[21]=t5.y; yt[22]=t5.z; yt[23]=t5.w;
    yp[0]=p0.x; yp[1]=p0.y; yp[2]=p0.z; yp[3]=p0.w;
    yp[4]=p1.x; yp[5]=p1.y; yp[6]=p1.z; yp[7]=p1.w;
    yp[8]=p2.x; yp[9]=p2.y; yp[10]=p2.z; yp[11]=p2.w;
    yp[12]=p3.x; yp[13]=p3.y; yp[14]=p3.z; yp[15]=p3.w;
    yp[16]=p4.x; yp[17]=p4.y; yp[18]=p4.z; yp[19]=p4.w;
    yp[20]=p5.x; yp[21]=p5.y; yp[22]=p5.z; yp[23]=p5.w;

    // daytime argmax, ascending h with strict > = first-max (jnp.argmax semantics)
    float tbest = yt[6]; int tt = 6;
#pragma unroll
    for (int h = 7; h <= 20; ++h) if (yt[h] > tbest) { tbest = yt[h]; tt = h; }
    float pbest = yp[6]; int pt = 6;
#pragma unroll
    for (int h = 7; h <= 20; ++h) if (yp[h] > pbest) { pbest = yp[h]; pt = h; }

    float se = 0.f, sw = 0.f;
#pragma unroll
    for (int h = 0; h < 24; ++h) {
        float bw = ((h >= 6) && (h <= 20)) ? 2.0f : 0.5f;
        float wgt = bw * (((h >= tt - 2) && (h <= tt + 2)) ? 3.0f : 1.0f);
        float dd = yp[h] - yt[h];
        se = fmaf(wgt * dd, dd, se);
        sw += wgt;
    }
    float te = fabsf((float)(pt - tt));
    if (!valid) { se = 0.f; sw = 0.f; te = 0.f; }

    // stash per-day peak stats for the in-block per-sample reduce
    if (tid < SPB * DPS) {
        float dpk = pbest - tbest;
        s_a[tid] = valid ? tbest : 0.f;
        s_p[tid] = valid ? dpk * dpk : 0.f;
    }

    // block reduce se/sw/te (8 waves)
#pragma unroll
    for (int o = 32; o > 0; o >>= 1) {
        se += __shfl_down(se, o, 64);
        sw += __shfl_down(sw, o, 64);
        te += __shfl_down(te, o, 64);
    }
    if (lane == 0) { s_red[0][wv] = se; s_red[1][wv] = sw; s_red[2][wv] = te; }
    __syncthreads();

    if (tid == 0) {
        float e = 0.f, w = 0.f, t = 0.f;
#pragma unroll
        for (int k = 0; k < 8; ++k) { e += s_red[0][k]; w += s_red[1][k]; t += s_red[2][k]; }
        SEb[blockIdx.x] = e; SWb[blockIdx.x] = w; Tb[blockIdx.x] = t;
    }

    // per-sample reduce: wave g (g<3) handles sample slot g
    if (wv < SPB) {
        const int bb = blockIdx.x * SPB + wv;
        const float* sa = s_a + wv * DPS;
        const float* sp = s_p + wv * DPS;
        float a = sa[lane] + sa[lane + 64];          // lane<64: both <168
        float p = sp[lane] + sp[lane + 64];
        if (lane < DPS - 128) { a += sa[lane + 128]; p += sp[lane + 128]; }
#pragma unroll
        for (int o = 32; o > 0; o >>= 1) {
            a += __shfl_down(a, o, 64);
            p += __shfl_down(p, o, 64);
        }
        if (lane == 0 && bb < nB) {
            A[bb] = a * (1.0f / (float)DPS);
            P[bb] = p;
        }
    }
}

// ========== kernel B: parallel rank-by-counting quantile ==========

__global__ __launch_bounds__(256) void rank_kernel(
    const float* __restrict__ A, float* __restrict__ qout, int nB)
{
    __shared__ float sA[NB_MAX];
    const int tid = threadIdx.x;

    for (int i = tid; i < nB; i += 256) sA[i] = A[i];
    __syncthreads();

    const int b = blockIdx.x * 64 + (tid >> 2);
    const int quar = tid & 3;
    if (b >= nB) return;
    const float v = sA[b];
    const int span = nB / 4;
    const float4* s4 = (const float4*)(sA + quar * span);

    int cl = 0, ce = 0;
    for (int i = 0; i < span / 4; ++i) {
        float4 x = s4[i];
        cl += (x.x < v) + (x.y < v) + (x.z < v) + (x.w < v);
        ce += (x.x == v) + (x.y == v) + (x.z == v) + (x.w == v);
    }
    cl += __shfl_xor(cl, 1, 64); ce += __shfl_xor(ce, 1, 64);
    cl += __shfl_xor(cl, 2, 64); ce += __shfl_xor(ce, 2, 64);

    if (quar == 0) {
        double pos = 0.75 * (double)(nB - 1);
        int lo = (int)pos;
        int hi = (lo + 1 < nB) ? lo + 1 : lo;
        if (lo >= cl && lo < cl + ce) qout[0] = v;
        if (hi >= cl && hi < cl + ce) qout[1] = v;
    }
}

// ========== kernel C: final scalar ==========

__device__ inline double block_reduce_d(double v, double* scratch, int tid) {
#pragma unroll
    for (int o = 32; o > 0; o >>= 1) v += __shfl_down(v, o, 64);
    if ((tid & 63) == 0) scratch[tid >> 6] = v;
    __syncthreads();
    double r = 0.0;
    if (tid == 0) r = scratch[0] + scratch[1] + scratch[2] + scratch[3];
    __syncthreads();
    return r;
}

__global__ __launch_bounds__(256) void final_kernel(
    const float* __restrict__ SEb, const float* __restrict__ SWb,
    const float* __restrict__ Tb, const float* __restrict__ P,
    const float* __restrict__ A, const float* __restrict__ qout,
    float* __restrict__ out, int nB, int nBlk)
{
    __shared__ double s_dred[4];
    const int tid = threadIdx.x;

    double pos = 0.75 * (double)(nB - 1);
    double frac = pos - (double)((int)pos);
    float thr = (float)((double)qout[0] + frac * ((double)qout[1] - (double)qout[0]));

    double se = 0.0, sw = 0.0, te = 0.0, wp = 0.0, wsum = 0.0;
    for (int i = tid; i < nBlk; i += 256) {
        se += (double)SEb[i];
        sw += (double)SWb[i];
        te += (double)Tb[i];
    }
    for (int b = tid; b < nB; b += 256) {
        float w = (A[b] > thr) ? 1.5f : 1.0f;
        wp   += (double)w * (double)P[b];
        wsum += (double)w;
    }
    se   = block_reduce_d(se,   s_dred, tid);
    sw   = block_reduce_d(sw,   s_dred, tid);
    te   = block_reduce_d(te,   s_dred, tid);
    wp   = block_reduce_d(wp,   s_dred, tid);
    wsum = block_reduce_d(wsum, s_dred, tid);

    if (tid == 0) {
        double L_overall = se / sw;
        double L_peak    = wp / ((double)DPS * wsum);
        double L_timing  = 10.0 * te / ((double)nB * (double)DPS);
        out[0] = (float)(L_overall + 2.0 * L_peak + L_timing);
    }
}

// ========== launcher ==========

extern "C" void kernel_launch(void* const* d_in, const int* in_sizes, int n_in,
                              void* d_out, int out_size, void* d_ws, size_t ws_size,
                              hipStream_t stream) {
    const float* y_pred = (const float*)d_in[0];
    const float* y_true = (const float*)d_in[1];
    int total = in_sizes[0];
    int nB = total / S_LEN;                       // 4096
    int nBlk = (nB + SPB - 1) / SPB;              // 1366

    float* ws  = (float*)d_ws;
    float* A   = ws;
    float* P   = A   + (size_t)nB;
    float* SEb = P   + (size_t)nB;
    float* SWb = SEb + (size_t)nBlk;
    float* Tb  = SWb + (size_t)nBlk;
    float* q   = Tb  + (size_t)nBlk;

    day_kernel<<<nBlk, 512, 0, stream>>>(y_true, y_pred, A, P, SEb, SWb, Tb, nB);
    rank_kernel<<<(nB + 63) / 64, 256, 0, stream>>>(A, q, nB);
    final_kernel<<<1, 256, 0, stream>>>(SEb, SWb, Tb, P, A, q, (float*)d_out, nB, nBlk);
}